// Round 1
// 483.238 us; speedup vs baseline: 1.1584x; 1.1584x over previous
//
#include <hip/hip_runtime.h>
#include <stdint.h>

#define OUT_F 4096
#define IN_F  4096
#define MROWS 8192            // 4*2048
#define NTILE (IN_F / 64)     // 64 K-tiles of 64

typedef __attribute__((ext_vector_type(8))) short  shortx8;   // 8 bf16 = 4 VGPRs
typedef __attribute__((ext_vector_type(4))) float  floatx4;

// fp32 -> bf16 bits, round-to-nearest-even
__device__ __forceinline__ unsigned short f32_to_bf16(float f) {
    unsigned int u = __builtin_bit_cast(unsigned int, f);
    u += 0x7FFFu + ((u >> 16) & 1u);
    return (unsigned short)(u >> 16);
}

// ---------------- fused preprocessing: x fp32->bf16  +  dequant W (unchanged) ----------------
#define CAST_BLOCKS 16384
__global__ void __launch_bounds__(256)
preprocess_kernel(const float* __restrict__ x, short* __restrict__ xb,
                  const int* __restrict__ q, const float* __restrict__ s,
                  short* __restrict__ wb) {
    const int b = blockIdx.x;
    if (b < CAST_BLOCKS) {
        int64_t i = ((int64_t)b * 256 + threadIdx.x) * 8;
        float4 v0 = *(const float4*)(x + i);
        float4 v1 = *(const float4*)(x + i + 4);
        shortx8 o;
        o[0] = (short)f32_to_bf16(v0.x); o[1] = (short)f32_to_bf16(v0.y);
        o[2] = (short)f32_to_bf16(v0.z); o[3] = (short)f32_to_bf16(v0.w);
        o[4] = (short)f32_to_bf16(v1.x); o[5] = (short)f32_to_bf16(v1.y);
        o[6] = (short)f32_to_bf16(v1.z); o[7] = (short)f32_to_bf16(v1.w);
        *(shortx8*)(xb + i) = o;
    } else {
        int64_t i = ((int64_t)(b - CAST_BLOCKS) * 256 + threadIdx.x) * 8;
        float sc = s[i >> 6];
        int4 a = *(const int4*)(q + i);
        int4 c = *(const int4*)(q + i + 4);
        shortx8 o;
        o[0] = (short)f32_to_bf16((float)a.x * sc); o[1] = (short)f32_to_bf16((float)a.y * sc);
        o[2] = (short)f32_to_bf16((float)a.z * sc); o[3] = (short)f32_to_bf16((float)a.w * sc);
        o[4] = (short)f32_to_bf16((float)c.x * sc); o[5] = (short)f32_to_bf16((float)c.y * sc);
        o[6] = (short)f32_to_bf16((float)c.z * sc); o[7] = (short)f32_to_bf16((float)c.w * sc);
        *(shortx8*)(wb + i) = o;
    }
}

// ---------------- 256x256 8-phase bf16 GEMM (T1+T2+T3+T4+T5) ----------------
// C[M,N] = A[M,K] * B[N,K]^T + bias.  BM=BN=256, BK=64, 8 waves (2M x 4N),
// per-wave output 128x64.  LDS 128 KiB: 2 bufs x (A 256x64 + B 256x64) bf16.
//
// LDS swizzle: 16B chunk of (row, c) stored at pos = c ^ (row & 7); staged by
// pre-swizzling the per-lane GLOBAL source (global_load_lds dest stays linear:
// wave base + lane*16 -> row = base/128 + lane>>3, pos = lane&7, so the lane
// fetches global chunk (lane&7)^(lane>>3)).  Read side applies the same XOR.
// 16 lanes of a ds_read_b128 then spread over all 8 chunk slots (2-way = free).
//
// Staging units per K-tile (each 16 KB = 2 global_load_lds/thread), ordered by
// last-read phase:  U0 = A rows {0-63,128-191}   (read P1)
//                   U1 = B rows {0-31,64-95,128-159,192-223}   (read P1)
//                   U2 = B rows {32-63,96-127,160-191,224-255} (read P2)
//                   U3 = A rows {64-127,192-255} (read P3)
// Phase p of tile t issues unit index 4t+6+p:
//   P1: U3(t+1)  P2: U0(t+2)  P3: U1(t+2)  P4: U2(t+2)
// Every region is overwritten >=1 barrier after its last read (issue-order
// argument; the async write cannot land before issue).  vmcnt(6) at end of
// each tile leaves exactly the 3 newest units (tile t+2's U0-U2) in flight and
// guarantees all of tile t+1 has landed.  Never vmcnt(0) in the main loop.

#define BAR()  asm volatile("s_barrier" ::: "memory")
#define VMC(n) asm volatile("s_waitcnt vmcnt(" #n ")" ::: "memory")

#define GLD(gp, lo) __builtin_amdgcn_global_load_lds( \
    (const __attribute__((address_space(1))) uint32_t*)(gp), \
    (__attribute__((address_space(3))) uint32_t*)(smem + (lo)), 16, 0, 0)

// d = K-tile offset (in units of 64 elems) from current gA/gB; BO = dest buffer byte offset
#define ST_U0(d, BO) do { GLD(gA + (d)*64,            (BO) + lbA        ); \
                          GLD(gA + (d)*64 + 128*IN_F, (BO) + lbA + 16384); } while (0)
#define ST_U3(d, BO) do { GLD(gA + (d)*64 +  64*IN_F, (BO) + lbA +  8192); \
                          GLD(gA + (d)*64 + 192*IN_F, (BO) + lbA + 24576); } while (0)
#define ST_U1(d, BO) do { GLD(gB + (d)*64,            (BO) + lbB        ); \
                          GLD(gB + (d)*64 + 128*IN_F, (BO) + lbB + 16384); } while (0)
#define ST_U2(d, BO) do { GLD(gB + (d)*64 +  32*IN_F, (BO) + lbB +  4096); \
                          GLD(gB + (d)*64 + 160*IN_F, (BO) + lbB + 20480); } while (0)

// frag reads: ks=1 flips chunk bit 2 -> XOR byte bit 6 of the swizzled address
#define LDA(mt, ks, BO) (*(const shortx8*)(smem + (BO) + ((offA + (mt)*2048) ^ ((ks)*64))))
#define LDB(nt, ks, BO) (*(const shortx8*)(smem + (BO) + ((offB + (nt)*2048) ^ ((ks)*64))))

// one C-quadrant x K=64: 16 MFMAs wrapped in setprio (T5)
#define MMAQ(MB, NB, BF) do { \
    __builtin_amdgcn_s_setprio(1); \
    _Pragma("unroll") \
    for (int ks_ = 0; ks_ < 2; ++ks_) \
      _Pragma("unroll") \
      for (int mt_ = 0; mt_ < 4; ++mt_) \
        _Pragma("unroll") \
        for (int nt_ = 0; nt_ < 2; ++nt_) \
          acc[(MB)+mt_][(NB)+nt_] = __builtin_amdgcn_mfma_f32_16x16x32_bf16( \
              af[mt_][ks_], BF[nt_][ks_], acc[(MB)+mt_][(NB)+nt_], 0, 0, 0); \
    __builtin_amdgcn_s_setprio(0); } while (0)

// one K-tile = 4 phases; each phase: ds-reads | stage issue | bar | MFMA | bar
#define TILE(BO, S1, S2, S3, S4, WFIN) do { \
    _Pragma("unroll") \
    for (int mt_ = 0; mt_ < 4; ++mt_) { af[mt_][0] = LDA(mt_, 0, BO); af[mt_][1] = LDA(mt_, 1, BO); } \
    b0[0][0] = LDB(0,0,BO); b0[0][1] = LDB(0,1,BO); \
    b0[1][0] = LDB(1,0,BO); b0[1][1] = LDB(1,1,BO); \
    S1; BAR(); \
    MMAQ(0, 0, b0); BAR(); \
    b1[0][0] = LDB(2,0,BO); b1[0][1] = LDB(2,1,BO); \
    b1[1][0] = LDB(3,0,BO); b1[1][1] = LDB(3,1,BO); \
    S2; BAR(); \
    MMAQ(0, 2, b1); BAR(); \
    _Pragma("unroll") \
    for (int mt_ = 0; mt_ < 4; ++mt_) { af[mt_][0] = LDA(mt_+4, 0, BO); af[mt_][1] = LDA(mt_+4, 1, BO); } \
    S3; BAR(); \
    MMAQ(4, 0, b0); BAR(); \
    S4; BAR(); \
    MMAQ(4, 2, b1); \
    WFIN; BAR(); \
  } while (0)

__global__ void __launch_bounds__(512, 2)
gemm_bf16_8phase(const short* __restrict__ A, const short* __restrict__ B,
                 const float* __restrict__ bias, float* __restrict__ C) {
    __shared__ __align__(16) char smem[131072];   // [buf][A 32K | B 32K]

    const int tid  = threadIdx.x;
    const int w    = tid >> 6;        // wave 0..7
    const int lane = tid & 63;
    const int wm   = w >> 2;          // 0..1
    const int wn   = w & 3;           // 0..3

    // T1: XCD-aware swizzle (512 wgs, 512%8==0 -> bijective)
    const int bid  = blockIdx.x;
    const int swz  = ((bid & 7) << 6) | (bid >> 3);
    const int row0 = (swz >> 4) << 8;   // M tile * 256
    const int col0 = (swz & 15) << 8;   // N tile * 256

    // ---- staging addresses: per-lane global (pre-swizzled), wave-uniform LDS base ----
    const int lrow = lane >> 3;                 // row within wave's 8-row slice
    const int lch  = (lane & 7) ^ lrow;         // swizzled k-chunk this lane fetches
    const short* gA = A + (int64_t)(row0 + w * 8 + lrow) * IN_F + lch * 8;
    const int bb   = w * 8 + (w >> 2) * 32;     // B row base: {0..31} u {64..95}
    const short* gB = B + (int64_t)(col0 + bb + lrow) * IN_F + lch * 8;
    const int lbA  = w * 1024;                  // A region base (bytes)
    const int lbB  = 32768 + bb * 128;          // B region base (bytes)

    // ---- read-side offsets (m89 fragment convention, same as verified 128^2 kernel) ----
    const int ml = lane & 15;
    const int q4 = lane >> 4;
    const int offA = (wm * 128 + ml) * 128 + ((q4 ^ (lane & 7)) << 4);
    const int offB = 32768 + (wn * 64 + ml) * 128 + ((q4 ^ (lane & 7)) << 4);

    floatx4 acc[8][4];
#pragma unroll
    for (int i = 0; i < 8; ++i)
#pragma unroll
        for (int j = 0; j < 4; ++j) acc[i][j] = (floatx4)(0.0f);

    shortx8 af[4][2], b0[2][2], b1[2][2];

    // prologue: tile0 -> buf0 (all 4 units), tile1 -> buf1 (U0..U2). 14 loads/wave;
    // vmcnt(6) -> tile0 fully landed, tile1's 3 units ride into the loop.
    ST_U0(0, 0); ST_U1(0, 0); ST_U2(0, 0); ST_U3(0, 0);
    ST_U0(1, 65536); ST_U1(1, 65536); ST_U2(1, 65536);
    VMC(6);
    BAR();

#pragma unroll 1
    for (int it = 0; it < (NTILE - 2) / 2; ++it) {     // tiles 0..61
        TILE(0,     ST_U3(1, 65536), ST_U0(2, 0),     ST_U1(2, 0),     ST_U2(2, 0),     VMC(6));
        TILE(65536, ST_U3(2, 0),     ST_U0(3, 65536), ST_U1(3, 65536), ST_U2(3, 65536), VMC(6));
        gA += 128; gB += 128;
    }
    // tail: tile 62 stages only tile 63's U3 then drains; tile 63 stages nothing
    TILE(0,     ST_U3(1, 65536), (void)0, (void)0, (void)0, VMC(0));
    TILE(65536, (void)0,         (void)0, (void)0, (void)0, (void)0);

    // epilogue: C/D layout col = lane&15, row = (lane>>4)*4 + reg  [m89/m91]
#pragma unroll
    for (int nt = 0; nt < 4; ++nt) {
        const int gcol = col0 + wn * 64 + nt * 16 + ml;
        const float bv = bias[gcol];
#pragma unroll
        for (int mt = 0; mt < 8; ++mt) {
            const int grow = row0 + wm * 128 + mt * 16 + q4 * 4;
            float* outp = C + (int64_t)grow * OUT_F + gcol;
#pragma unroll
            for (int r = 0; r < 4; ++r)
                outp[(int64_t)r * OUT_F] = acc[mt][nt][r] + bv;
        }
    }
}

extern "C" void kernel_launch(void* const* d_in, const int* in_sizes, int n_in,
                              void* d_out, int out_size, void* d_ws, size_t ws_size,
                              hipStream_t stream) {
    const float* x    = (const float*)d_in[0];
    const int*   qw   = (const int*)d_in[1];
    const float* sc   = (const float*)d_in[2];
    const float* bias = (const float*)d_in[3];
    float*       out  = (float*)d_out;

    // workspace: [x_bf16: 64 MiB][w_bf16: 32 MiB]
    short* xb = (short*)d_ws;
    short* wb = (short*)((char*)d_ws + (size_t)MROWS * IN_F * sizeof(short));

    preprocess_kernel<<<CAST_BLOCKS + (OUT_F * IN_F) / 8 / 256, 256, 0, stream>>>(
        x, xb, qw, sc, wb);

    gemm_bf16_8phase<<<dim3((MROWS / 256) * (OUT_F / 256)), dim3(512), 0, stream>>>(
        xb, wb, bias, out);
}

// Round 2
// 479.213 us; speedup vs baseline: 1.1682x; 1.0084x over previous
//
#include <hip/hip_runtime.h>
#include <stdint.h>

#define OUT_F 4096
#define IN_F  4096
#define MROWS 8192            // 4*2048
#define NTILE (IN_F / 64)     // 64 K-tiles of 64

typedef __attribute__((ext_vector_type(8))) short  shortx8;   // 8 bf16 = 4 VGPRs
typedef __attribute__((ext_vector_type(4))) float  floatx4;

// fp32 -> bf16 bits, round-to-nearest-even
__device__ __forceinline__ unsigned short f32_to_bf16(float f) {
    unsigned int u = __builtin_bit_cast(unsigned int, f);
    u += 0x7FFFu + ((u >> 16) & 1u);
    return (unsigned short)(u >> 16);
}

// ---------------- fused preprocessing: x fp32->bf16  +  dequant W (unchanged) ----------------
#define CAST_BLOCKS 16384
__global__ void __launch_bounds__(256)
preprocess_kernel(const float* __restrict__ x, short* __restrict__ xb,
                  const int* __restrict__ q, const float* __restrict__ s,
                  short* __restrict__ wb) {
    const int b = blockIdx.x;
    if (b < CAST_BLOCKS) {
        int64_t i = ((int64_t)b * 256 + threadIdx.x) * 8;
        float4 v0 = *(const float4*)(x + i);
        float4 v1 = *(const float4*)(x + i + 4);
        shortx8 o;
        o[0] = (short)f32_to_bf16(v0.x); o[1] = (short)f32_to_bf16(v0.y);
        o[2] = (short)f32_to_bf16(v0.z); o[3] = (short)f32_to_bf16(v0.w);
        o[4] = (short)f32_to_bf16(v1.x); o[5] = (short)f32_to_bf16(v1.y);
        o[6] = (short)f32_to_bf16(v1.z); o[7] = (short)f32_to_bf16(v1.w);
        *(shortx8*)(xb + i) = o;
    } else {
        int64_t i = ((int64_t)(b - CAST_BLOCKS) * 256 + threadIdx.x) * 8;
        float sc = s[i >> 6];
        int4 a = *(const int4*)(q + i);
        int4 c = *(const int4*)(q + i + 4);
        shortx8 o;
        o[0] = (short)f32_to_bf16((float)a.x * sc); o[1] = (short)f32_to_bf16((float)a.y * sc);
        o[2] = (short)f32_to_bf16((float)a.z * sc); o[3] = (short)f32_to_bf16((float)a.w * sc);
        o[4] = (short)f32_to_bf16((float)c.x * sc); o[5] = (short)f32_to_bf16((float)c.y * sc);
        o[6] = (short)f32_to_bf16((float)c.z * sc); o[7] = (short)f32_to_bf16((float)c.w * sc);
        *(shortx8*)(wb + i) = o;
    }
}

// ---------------- 256x256 8-phase bf16 GEMM, rotated read schedule ----------------
// C[M,N] = A[M,K] * B[N,K]^T + bias.  BM=BN=256, BK=64, 8 waves (2M x 4N),
// per-wave output 128x64.  LDS 128 KiB: 2 bufs x (A 256x64 + B 256x64) bf16.
//
// Phase schedule (tile t in CUR, t+1 in NXT), reads feed the NEXT MFMA cluster:
//   P1: vmcnt(8); rd b1(t)<-CUR;  stage U3(t+1)->NXT; BAR; MMAQ(0,0:af03xb0);              BAR
//   P2: vmcnt(8);                 stage U0(t+2)->CUR; BAR; MMAQ(0,2:af03xb1); rd af47(t);  BAR
//   P3: vmcnt(8);                 stage U1(t+2)->CUR; BAR; MMAQ(4,0:af47xb0); rd b0(t+1);  BAR
//   P4: vmcnt(6);                 stage U2(t+2)->CUR; BAR; MMAQ(4,2:af47xb1); rd af03(t+1);BAR
// Post-MFMA reads are register-WAR-safe (shared af/b regs die at that MFMA), so
// register footprint is unchanged vs the 49%-util version.  Every ds_read has a
// full phase (~200cyc) before its consuming MFMA -> lgkm waits ~0; reads issue in
// the MFMA/barrier shadow.  Each vmcnt waits on loads issued 4-6 phases (~1000cyc)
// earlier >= HBM latency -> ~0 vm stalls (the old single vmcnt(6) waited on a
// 3-phase-old load: ~300cyc stall/tile).
//
// Cross-wave landing proofs (writer's vmcnt proving unit retired BEFORE a barrier
// preceding any reader's ds_read; vmcnt retires in issue order):
//   b1(t)@P1    <- U2(t):   vmcnt(6)@P4(t-1) (6 newer loads)  -> proven pre P4.BARs
//   af47(t)@P2  <- U3(t):   vmcnt(8)@P2(t)   (8 newer)        -> proven pre P2.BAR1
//   b0(t+1)@P3  <- U1(t+1): vmcnt(8)@P3(t)   (8 newer incl. U1(t+2) staged pre-BAR1)
//   af03(t+1)@P4<- U0(t+1): vmcnt(6)@P4(t)   (>=12 newer)     -> proven pre P4.BAR1
// LDS WAR (stage overwrites vs reads): each overwrite issues >=1 barrier after the
// ds_read of that region was lgkm-pinned by its consuming MFMA.  All verified.

#define BAR()  asm volatile("s_barrier" ::: "memory")
#define VMC(n) asm volatile("s_waitcnt vmcnt(" #n ")" ::: "memory")

#define GLD(gp, lo) __builtin_amdgcn_global_load_lds( \
    (const __attribute__((address_space(1))) uint32_t*)(gp), \
    (__attribute__((address_space(3))) uint32_t*)(smem + (lo)), 16, 0, 0)

// d = K-tile offset (units of 64 elems) from current gA/gB; BO = dest buffer byte offset
#define ST_U0(d, BO) do { GLD(gA + (d)*64,            (BO) + lbA        ); \
                          GLD(gA + (d)*64 + 128*IN_F, (BO) + lbA + 16384); } while (0)
#define ST_U3(d, BO) do { GLD(gA + (d)*64 +  64*IN_F, (BO) + lbA +  8192); \
                          GLD(gA + (d)*64 + 192*IN_F, (BO) + lbA + 24576); } while (0)
#define ST_U1(d, BO) do { GLD(gB + (d)*64,            (BO) + lbB        ); \
                          GLD(gB + (d)*64 + 128*IN_F, (BO) + lbB + 16384); } while (0)
#define ST_U2(d, BO) do { GLD(gB + (d)*64 +  32*IN_F, (BO) + lbB +  4096); \
                          GLD(gB + (d)*64 + 160*IN_F, (BO) + lbB + 20480); } while (0)

// ds_read addressing: ks-XOR pre-folded into two base offsets -> every read is
// base + compile-time displacement (immediate-foldable, no per-read VALU).
// Equivalent to old ((off + mt*2048) ^ (ks*64)): fields are carry-disjoint.
#define LDA(mt, KS, BO, EX) (*(const shortx8*)(smem + (BO) + ((KS) ? offA1 : offA0) + (EX) + (mt)*2048))
#define LDB(nt, KS, BO)     (*(const shortx8*)(smem + (BO) + ((KS) ? offB1 : offB0) + (nt)*2048))

#define RD_A03(BO) do { _Pragma("unroll") \
    for (int mt_ = 0; mt_ < 4; ++mt_) { af[mt_][0] = LDA(mt_,0,BO,0);    af[mt_][1] = LDA(mt_,1,BO,0);    } } while (0)
#define RD_A47(BO) do { _Pragma("unroll") \
    for (int mt_ = 0; mt_ < 4; ++mt_) { af[mt_][0] = LDA(mt_,0,BO,8192); af[mt_][1] = LDA(mt_,1,BO,8192); } } while (0)
#define RD_B0(BO) do { b0[0][0]=LDB(0,0,BO); b0[0][1]=LDB(0,1,BO); \
                       b0[1][0]=LDB(1,0,BO); b0[1][1]=LDB(1,1,BO); } while (0)
#define RD_B1(BO) do { b1[0][0]=LDB(2,0,BO); b1[0][1]=LDB(2,1,BO); \
                       b1[1][0]=LDB(3,0,BO); b1[1][1]=LDB(3,1,BO); } while (0)

// one C-quadrant x K=64: 16 MFMAs wrapped in setprio (T5)
#define MMAQ(MB, NB, BF) do { \
    __builtin_amdgcn_s_setprio(1); \
    _Pragma("unroll") \
    for (int ks_ = 0; ks_ < 2; ++ks_) \
      _Pragma("unroll") \
      for (int mt_ = 0; mt_ < 4; ++mt_) \
        _Pragma("unroll") \
        for (int nt_ = 0; nt_ < 2; ++nt_) \
          acc[(MB)+mt_][(NB)+nt_] = __builtin_amdgcn_mfma_f32_16x16x32_bf16( \
              af[mt_][ks_], BF[nt_][ks_], acc[(MB)+mt_][(NB)+nt_], 0, 0, 0); \
    __builtin_amdgcn_s_setprio(0); } while (0)

#define PH1(CUR,NXT,dN)  do { VMC(8); RD_B1(CUR); ST_U3(dN,NXT);  BAR(); MMAQ(0,0,b0);              BAR(); } while (0)
#define PH2(CUR,dNN)     do { VMC(8);             ST_U0(dNN,CUR); BAR(); MMAQ(0,2,b1); RD_A47(CUR); BAR(); } while (0)
#define PH3(CUR,NXT,dNN) do { VMC(8);             ST_U1(dNN,CUR); BAR(); MMAQ(4,0,b0); RD_B0(NXT);  BAR(); } while (0)
#define PH4(CUR,NXT,dNN) do { VMC(6);             ST_U2(dNN,CUR); BAR(); MMAQ(4,2,b1); RD_A03(NXT); BAR(); } while (0)

__global__ void __launch_bounds__(512, 2)
gemm_bf16_8phase(const short* __restrict__ A, const short* __restrict__ B,
                 const float* __restrict__ bias, float* __restrict__ C) {
    __shared__ __align__(16) char smem[131072];   // [buf][A 32K | B 32K]

    const int tid  = threadIdx.x;
    const int w    = tid >> 6;        // wave 0..7
    const int lane = tid & 63;
    const int wm   = w >> 2;          // 0..1
    const int wn   = w & 3;           // 0..3

    // T1: XCD-aware swizzle (512 wgs, 512%8==0 -> bijective)
    const int bid  = blockIdx.x;
    const int swz  = ((bid & 7) << 6) | (bid >> 3);
    const int row0 = (swz >> 4) << 8;   // M tile * 256
    const int col0 = (swz & 15) << 8;   // N tile * 256

    // ---- staging: per-lane pre-swizzled global src, wave-uniform linear LDS dest ----
    const int lrow = lane >> 3;                 // row within wave's 8-row slice
    const int lch  = (lane & 7) ^ lrow;         // swizzled k-chunk this lane fetches
    const short* gA = A + (int64_t)(row0 + w * 8 + lrow) * IN_F + lch * 8;
    const int bb   = w * 8 + (w >> 2) * 32;     // B row base: {0..31} u {64..95}
    const short* gB = B + (int64_t)(col0 + bb + lrow) * IN_F + lch * 8;
    const int lbA  = w * 1024;                  // A region base (bytes)
    const int lbB  = 32768 + bb * 128;          // B region base (bytes)

    // ---- read-side offsets (m89 fragment convention; identical math to passing kernel) ----
    const int ml = lane & 15;
    const int q4 = lane >> 4;
    const int offA0 = (wm * 128 + ml) * 128 + ((q4 ^ (lane & 7)) << 4);
    const int offA1 = offA0 ^ 64;
    const int offB0 = 32768 + (wn * 64 + ml) * 128 + ((q4 ^ (lane & 7)) << 4);
    const int offB1 = offB0 ^ 64;

    floatx4 acc[8][4];
#pragma unroll
    for (int i = 0; i < 8; ++i)
#pragma unroll
        for (int j = 0; j < 4; ++j) acc[i][j] = (floatx4)(0.0f);

    shortx8 af[4][2], b0[2][2], b1[2][2];

    // prologue: tile0 all 4 units -> buf0; tile1 U0-U2 -> buf1 (14 loads/wave).
    // vmcnt(6) => first 8 loads (all of tile0) retired for every wave; BAR publishes.
    ST_U0(0, 0); ST_U1(0, 0); ST_U2(0, 0); ST_U3(0, 0);
    ST_U0(1, 65536); ST_U1(1, 65536); ST_U2(1, 65536);
    VMC(6);
    BAR();
    RD_A03(0);   // af03(0)
    RD_B0(0);    // b0(0)

#pragma unroll 1
    for (int it = 0; it < 31; ++it) {            // tiles 0..61; stages reach k-tile 63
        PH1(0, 65536, 1); PH2(0, 2); PH3(0, 65536, 2); PH4(0, 65536, 2);
        PH1(65536, 0, 2); PH2(65536, 3); PH3(65536, 0, 3); PH4(65536, 0, 3);
        gA += 128; gB += 128;                    // advance 2 K-tiles
    }
    // ---- tail: tile 62 (CUR=0) stages only U3(63); vmcnt ladder 8/8/4/2 ----
    VMC(8); RD_B1(0); ST_U3(1, 65536); BAR(); MMAQ(0,0,b0);               BAR();
    VMC(8);                            BAR(); MMAQ(0,2,b1); RD_A47(0);    BAR();
    VMC(4);                            BAR(); MMAQ(4,0,b0); RD_B0(65536); BAR();
    VMC(2);                            BAR(); MMAQ(4,2,b1); RD_A03(65536);BAR();
    // ---- tile 63 (buf1): everything landed; single vmcnt(0)+BAR then no barriers ----
    VMC(0); BAR();
    RD_B1(65536);
    MMAQ(0,0,b0); MMAQ(0,2,b1);
    RD_A47(65536);                               // reg-WAR after MMAQ(0,2)
    MMAQ(4,0,b0); MMAQ(4,2,b1);

    // epilogue: C/D layout col = lane&15, row = (lane>>4)*4 + reg  [m89/m91]
#pragma unroll
    for (int nt = 0; nt < 4; ++nt) {
        const int gcol = col0 + wn * 64 + nt * 16 + ml;
        const float bv = bias[gcol];
#pragma unroll
        for (int mt = 0; mt < 8; ++mt) {
            const int grow = row0 + wm * 128 + mt * 16 + q4 * 4;
            float* outp = C + (int64_t)grow * OUT_F + gcol;
#pragma unroll
            for (int r = 0; r < 4; ++r)
                outp[(int64_t)r * OUT_F] = acc[mt][nt][r] + bv;
        }
    }
}

extern "C" void kernel_launch(void* const* d_in, const int* in_sizes, int n_in,
                              void* d_out, int out_size, void* d_ws, size_t ws_size,
                              hipStream_t stream) {
    const float* x    = (const float*)d_in[0];
    const int*   qw   = (const int*)d_in[1];
    const float* sc   = (const float*)d_in[2];
    const float* bias = (const float*)d_in[3];
    float*       out  = (float*)d_out;

    // workspace: [x_bf16: 64 MiB][w_bf16: 32 MiB]
    short* xb = (short*)d_ws;
    short* wb = (short*)((char*)d_ws + (size_t)MROWS * IN_F * sizeof(short));

    preprocess_kernel<<<CAST_BLOCKS + (OUT_F * IN_F) / 8 / 256, 256, 0, stream>>>(
        x, xb, qw, sc, wb);

    gemm_bf16_8phase<<<dim3((MROWS / 256) * (OUT_F / 256)), dim3(512), 0, stream>>>(
        xb, wb, bias, out);
}

// Round 3
// 472.101 us; speedup vs baseline: 1.1858x; 1.0151x over previous
//
#include <hip/hip_runtime.h>
#include <stdint.h>

#define OUT_F 4096
#define IN_F  4096
#define MROWS 8192            // 4*2048
#define NTILE (IN_F / 64)     // 64 K-tiles of 64

typedef __attribute__((ext_vector_type(8))) short  shortx8;   // 8 bf16 = 4 VGPRs
typedef __attribute__((ext_vector_type(4))) float  floatx4;

// fp32 -> bf16 bits, round-to-nearest-even
__device__ __forceinline__ unsigned short f32_to_bf16(float f) {
    unsigned int u = __builtin_bit_cast(unsigned int, f);
    u += 0x7FFFu + ((u >> 16) & 1u);
    return (unsigned short)(u >> 16);
}

// ---------------- fused preprocessing: x fp32->bf16  +  dequant W ----------------
// 16 elems/thread (was 8): halves block count + instruction count.
#define CAST_BLOCKS 8192
__global__ void __launch_bounds__(256)
preprocess_kernel(const float* __restrict__ x, short* __restrict__ xb,
                  const int* __restrict__ q, const float* __restrict__ s,
                  short* __restrict__ wb) {
    const int b = blockIdx.x;
    if (b < CAST_BLOCKS) {
        int64_t i = ((int64_t)b * 256 + threadIdx.x) * 16;
        float4 v0 = *(const float4*)(x + i);
        float4 v1 = *(const float4*)(x + i + 4);
        float4 v2 = *(const float4*)(x + i + 8);
        float4 v3 = *(const float4*)(x + i + 12);
        shortx8 o0, o1;
        o0[0] = (short)f32_to_bf16(v0.x); o0[1] = (short)f32_to_bf16(v0.y);
        o0[2] = (short)f32_to_bf16(v0.z); o0[3] = (short)f32_to_bf16(v0.w);
        o0[4] = (short)f32_to_bf16(v1.x); o0[5] = (short)f32_to_bf16(v1.y);
        o0[6] = (short)f32_to_bf16(v1.z); o0[7] = (short)f32_to_bf16(v1.w);
        o1[0] = (short)f32_to_bf16(v2.x); o1[1] = (short)f32_to_bf16(v2.y);
        o1[2] = (short)f32_to_bf16(v2.z); o1[3] = (short)f32_to_bf16(v2.w);
        o1[4] = (short)f32_to_bf16(v3.x); o1[5] = (short)f32_to_bf16(v3.y);
        o1[6] = (short)f32_to_bf16(v3.z); o1[7] = (short)f32_to_bf16(v3.w);
        *(shortx8*)(xb + i) = o0;
        *(shortx8*)(xb + i + 8) = o1;
    } else {
        int64_t i = ((int64_t)(b - CAST_BLOCKS) * 256 + threadIdx.x) * 16;
        float sc = s[i >> 6];              // 16 elems always within one 64-block
        int4 a0 = *(const int4*)(q + i);
        int4 a1 = *(const int4*)(q + i + 4);
        int4 a2 = *(const int4*)(q + i + 8);
        int4 a3 = *(const int4*)(q + i + 12);
        shortx8 o0, o1;
        o0[0] = (short)f32_to_bf16((float)a0.x * sc); o0[1] = (short)f32_to_bf16((float)a0.y * sc);
        o0[2] = (short)f32_to_bf16((float)a0.z * sc); o0[3] = (short)f32_to_bf16((float)a0.w * sc);
        o0[4] = (short)f32_to_bf16((float)a1.x * sc); o0[5] = (short)f32_to_bf16((float)a1.y * sc);
        o0[6] = (short)f32_to_bf16((float)a1.z * sc); o0[7] = (short)f32_to_bf16((float)a1.w * sc);
        o1[0] = (short)f32_to_bf16((float)a2.x * sc); o1[1] = (short)f32_to_bf16((float)a2.y * sc);
        o1[2] = (short)f32_to_bf16((float)a2.z * sc); o1[3] = (short)f32_to_bf16((float)a2.w * sc);
        o1[4] = (short)f32_to_bf16((float)a3.x * sc); o1[5] = (short)f32_to_bf16((float)a3.y * sc);
        o1[6] = (short)f32_to_bf16((float)a3.z * sc); o1[7] = (short)f32_to_bf16((float)a3.w * sc);
        *(shortx8*)(wb + i) = o0;
        *(shortx8*)(wb + i + 8) = o1;
    }
}

// ---------------- 256x256 8-phase bf16 GEMM, stage-in-MFMA-shadow ----------------
// C[M,N] = A[M,K] * B[N,K]^T + bias.  BM=BN=256, BK=64, 8 waves (2M x 4N),
// per-wave output 128x64.  LDS 128 KiB: 2 bufs x (A 256x64 + B 256x64) bf16.
//
// Phase (tile t in CUR, t+1 in NXT):  VMC -> BAR -> ST || MFMA || RD -> BAR
//   P1: VMC(8);  BAR; ST U3(t+1)->NXT; MMAQ(0,0:af03xb0); RD b1(t)<-CUR;   BAR
//   P2: VMC(8);  BAR; ST U0(t+2)->CUR; MMAQ(0,2:af03xb1); RD af47(t);      BAR
//   P3: VMC(6);  BAR; ST U1(t+2)->CUR; MMAQ(4,0:af47xb0); RD b0(t+1)<-NXT; BAR
//   P4: VMC(10); BAR; ST U2(t+2)->CUR; MMAQ(4,2:af47xb1); RD a03(t+1)<-NXT;BAR
// Stage-issue now overlaps the MFMA cluster instead of serializing pre-barrier.
//
// Issue ledger (2 loads/unit): ... P1(t-1):U3(t), P2(t-1):U0(t+1), P3(t-1):U1(t+1),
//   P4(t-1):U2(t+1), P1(t):U3(t+1), P2(t):U0(t+2), P3(t):U1(t+2), P4(t):U2(t+2) ...
// VMC proofs (outstanding counted at VMC, before this phase's own ST):
//   P1 needs U2(t):   newer = U3(t),U0/U1/U2(t+1) = 8  -> VMC(8), issued 5 phases back
//   P2 needs U3(t):   newer = U0/U1/U2/U3(t+1)    = 8  -> VMC(8), 4 phases back
//   P3 needs U1(t+1): newer = U2(t+1),U3(t+1),U0(t+2)=6-> VMC(6), 4 phases back
//   P4 needs U0(t+1): newer = U1/U2/U3(t+1),U0/U1(t+2)=10 -> VMC(10), 6 phases back
// All waits target loads >=4 phases (~2200cyc) old >= HBM latency -> ~0 vm stalls.
// Cross-wave: writer's VMC is pre-BAR, reader's RD post-BAR -> ordered.
// LDS WAR: every ST overwrite now lands >=2 barriers after the region's last
// ds_read issue (one more than R2) -> strictly safer.

#define BAR()  asm volatile("s_barrier" ::: "memory")
#define VMC(n) asm volatile("s_waitcnt vmcnt(" #n ")" ::: "memory")

#define GLD(gp, lo) __builtin_amdgcn_global_load_lds( \
    (const __attribute__((address_space(1))) uint32_t*)(gp), \
    (__attribute__((address_space(3))) uint32_t*)(smem + (lo)), 16, 0, 0)

// d = K-tile offset (units of 64 elems) from current gA/gB; BO = dest buffer byte offset
#define ST_U0(d, BO) do { GLD(gA + (d)*64,            (BO) + lbA        ); \
                          GLD(gA + (d)*64 + 128*IN_F, (BO) + lbA + 16384); } while (0)
#define ST_U3(d, BO) do { GLD(gA + (d)*64 +  64*IN_F, (BO) + lbA +  8192); \
                          GLD(gA + (d)*64 + 192*IN_F, (BO) + lbA + 24576); } while (0)
#define ST_U1(d, BO) do { GLD(gB + (d)*64,            (BO) + lbB        ); \
                          GLD(gB + (d)*64 + 128*IN_F, (BO) + lbB + 16384); } while (0)
#define ST_U2(d, BO) do { GLD(gB + (d)*64 +  32*IN_F, (BO) + lbB +  4096); \
                          GLD(gB + (d)*64 + 160*IN_F, (BO) + lbB + 20480); } while (0)

// ds_read addressing: ks-XOR pre-folded into two base offsets -> base + imm disp.
#define LDA(mt, KS, BO, EX) (*(const shortx8*)(smem + (BO) + ((KS) ? offA1 : offA0) + (EX) + (mt)*2048))
#define LDB(nt, KS, BO)     (*(const shortx8*)(smem + (BO) + ((KS) ? offB1 : offB0) + (nt)*2048))

#define RD_A03(BO) do { _Pragma("unroll") \
    for (int mt_ = 0; mt_ < 4; ++mt_) { af[mt_][0] = LDA(mt_,0,BO,0);    af[mt_][1] = LDA(mt_,1,BO,0);    } } while (0)
#define RD_A47(BO) do { _Pragma("unroll") \
    for (int mt_ = 0; mt_ < 4; ++mt_) { af[mt_][0] = LDA(mt_,0,BO,8192); af[mt_][1] = LDA(mt_,1,BO,8192); } } while (0)
#define RD_B0(BO) do { b0[0][0]=LDB(0,0,BO); b0[0][1]=LDB(0,1,BO); \
                       b0[1][0]=LDB(1,0,BO); b0[1][1]=LDB(1,1,BO); } while (0)
#define RD_B1(BO) do { b1[0][0]=LDB(2,0,BO); b1[0][1]=LDB(2,1,BO); \
                       b1[1][0]=LDB(3,0,BO); b1[1][1]=LDB(3,1,BO); } while (0)

// one C-quadrant x K=64: 16 MFMAs wrapped in setprio (T5)
#define MMAQ(MB, NB, BF) do { \
    __builtin_amdgcn_s_setprio(1); \
    _Pragma("unroll") \
    for (int ks_ = 0; ks_ < 2; ++ks_) \
      _Pragma("unroll") \
      for (int mt_ = 0; mt_ < 4; ++mt_) \
        _Pragma("unroll") \
        for (int nt_ = 0; nt_ < 2; ++nt_) \
          acc[(MB)+mt_][(NB)+nt_] = __builtin_amdgcn_mfma_f32_16x16x32_bf16( \
              af[mt_][ks_], BF[nt_][ks_], acc[(MB)+mt_][(NB)+nt_], 0, 0, 0); \
    __builtin_amdgcn_s_setprio(0); } while (0)

#define PH1(CUR,NXT,dN)  do { VMC(8);  BAR(); ST_U3(dN,NXT);  MMAQ(0,0,b0); RD_B1(CUR);  BAR(); } while (0)
#define PH2(CUR,dNN)     do { VMC(8);  BAR(); ST_U0(dNN,CUR); MMAQ(0,2,b1); RD_A47(CUR); BAR(); } while (0)
#define PH3(CUR,NXT,dNN) do { VMC(6);  BAR(); ST_U1(dNN,CUR); MMAQ(4,0,b0); RD_B0(NXT);  BAR(); } while (0)
#define PH4(CUR,NXT,dNN) do { VMC(10); BAR(); ST_U2(dNN,CUR); MMAQ(4,2,b1); RD_A03(NXT); BAR(); } while (0)

__global__ void __launch_bounds__(512, 2)
gemm_bf16_8phase(const short* __restrict__ A, const short* __restrict__ B,
                 const float* __restrict__ bias, float* __restrict__ C) {
    __shared__ __align__(16) char smem[131072];   // [buf][A 32K | B 32K]

    const int tid  = threadIdx.x;
    const int w    = tid >> 6;        // wave 0..7
    const int lane = tid & 63;
    const int wm   = w >> 2;          // 0..1
    const int wn   = w & 3;           // 0..3

    // T1: XCD-aware swizzle (512 wgs, 512%8==0 -> bijective)
    const int bid  = blockIdx.x;
    const int swz  = ((bid & 7) << 6) | (bid >> 3);
    const int row0 = (swz >> 4) << 8;   // M tile * 256
    const int col0 = (swz & 15) << 8;   // N tile * 256

    // ---- staging: per-lane pre-swizzled global src, wave-uniform linear LDS dest ----
    const int lrow = lane >> 3;                 // row within wave's 8-row slice
    const int lch  = (lane & 7) ^ lrow;         // swizzled k-chunk this lane fetches
    const short* gA = A + (int64_t)(row0 + w * 8 + lrow) * IN_F + lch * 8;
    const int bb   = w * 8 + (w >> 2) * 32;     // B row base: {0..31} u {64..95}
    const short* gB = B + (int64_t)(col0 + bb + lrow) * IN_F + lch * 8;
    const int lbA  = w * 1024;                  // A region base (bytes)
    const int lbB  = 32768 + bb * 128;          // B region base (bytes)

    // ---- read-side offsets (m89 fragment convention) ----
    const int ml = lane & 15;
    const int q4 = lane >> 4;
    const int offA0 = (wm * 128 + ml) * 128 + ((q4 ^ (lane & 7)) << 4);
    const int offA1 = offA0 ^ 64;
    const int offB0 = 32768 + (wn * 64 + ml) * 128 + ((q4 ^ (lane & 7)) << 4);
    const int offB1 = offB0 ^ 64;

    floatx4 acc[8][4];
#pragma unroll
    for (int i = 0; i < 8; ++i)
#pragma unroll
        for (int j = 0; j < 4; ++j) acc[i][j] = (floatx4)(0.0f);

    shortx8 af[4][2], b0[2][2], b1[2][2];

    // prologue: tile0 all 4 units -> buf0; tile1 U0-U2 -> buf1 (14 loads/wave).
    // vmcnt(6) => all of tile0 retired for every wave; BAR publishes.
    ST_U0(0, 0); ST_U1(0, 0); ST_U2(0, 0); ST_U3(0, 0);
    ST_U0(1, 65536); ST_U1(1, 65536); ST_U2(1, 65536);
    VMC(6);
    BAR();
    RD_A03(0);   // af03(0)
    RD_B0(0);    // b0(0)

#pragma unroll 1
    for (int it = 0; it < 31; ++it) {            // tiles 0..61; stages reach k-tile 63
        PH1(0, 65536, 1); PH2(0, 2); PH3(0, 65536, 2); PH4(0, 65536, 2);
        PH1(65536, 0, 2); PH2(65536, 3); PH3(65536, 0, 3); PH4(65536, 0, 3);
        gA += 128; gB += 128;                    // advance 2 K-tiles
    }
    // ---- tail: tile 62 (buf0) stages only U3(63); ladder re-derived:
    //   P1: outstanding pre-ST = U3(62),U0(63),U1(63),U2(63) = 8 -> VMC(8) proves U2(62)
    //   P2: outstanding = 8 + U3(63) = 10 -> VMC(8) proves U3(62)
    //   P3: VMC(4) proves U1(63)   P4: VMC(2) proves U2(63) (superset of needed U0(63))
    VMC(8); BAR(); ST_U3(1, 65536); MMAQ(0,0,b0); RD_B1(0);      BAR();
    VMC(8); BAR();                  MMAQ(0,2,b1); RD_A47(0);     BAR();
    VMC(4); BAR();                  MMAQ(4,0,b0); RD_B0(65536);  BAR();
    VMC(2); BAR();                  MMAQ(4,2,b1); RD_A03(65536); BAR();
    // ---- tile 63 (buf1): everything landed after VMC(0) ----
    VMC(0); BAR();
    RD_B1(65536);
    MMAQ(0,0,b0); MMAQ(0,2,b1);
    RD_A47(65536);                               // reg-WAR after MMAQ(0,2)
    MMAQ(4,0,b0); MMAQ(4,2,b1);

    // epilogue: C/D layout col = lane&15, row = (lane>>4)*4 + reg  [m89/m91]
#pragma unroll
    for (int nt = 0; nt < 4; ++nt) {
        const int gcol = col0 + wn * 64 + nt * 16 + ml;
        const float bv = bias[gcol];
#pragma unroll
        for (int mt = 0; mt < 8; ++mt) {
            const int grow = row0 + wm * 128 + mt * 16 + q4 * 4;
            float* outp = C + (int64_t)grow * OUT_F + gcol;
#pragma unroll
            for (int r = 0; r < 4; ++r)
                outp[(int64_t)r * OUT_F] = acc[mt][nt][r] + bv;
        }
    }
}

extern "C" void kernel_launch(void* const* d_in, const int* in_sizes, int n_in,
                              void* d_out, int out_size, void* d_ws, size_t ws_size,
                              hipStream_t stream) {
    const float* x    = (const float*)d_in[0];
    const int*   qw   = (const int*)d_in[1];
    const float* sc   = (const float*)d_in[2];
    const float* bias = (const float*)d_in[3];
    float*       out  = (float*)d_out;

    // workspace: [x_bf16: 64 MiB][w_bf16: 32 MiB]
    short* xb = (short*)d_ws;
    short* wb = (short*)((char*)d_ws + (size_t)MROWS * IN_F * sizeof(short));

    preprocess_kernel<<<CAST_BLOCKS + (OUT_F * IN_F) / 16 / 256, 256, 0, stream>>>(
        x, xb, qw, sc, wb);

    gemm_bf16_8phase<<<dim3((MROWS / 256) * (OUT_F / 256)), dim3(512), 0, stream>>>(
        xb, wb, bias, out);
}